// Round 7
// baseline (220.572 us; speedup 1.0000x reference)
//
#include <hip/hip_runtime.h>

typedef __attribute__((ext_vector_type(8))) short bf16x8;
typedef __attribute__((ext_vector_type(4))) short bf16x4;
typedef __attribute__((ext_vector_type(4))) float f32x4;

#define DEVI __device__ __forceinline__

constexpr int Bsz = 2, Ssz = 2048, HID = 1024, NH = 16, NKV = 4, Dh = 64;
constexpr int QKVC = NH * Dh + 2 * NKV * Dh;  // 1536
constexpr int WINDOW = 1024;
constexpr float SCALE_ = 0.125f;
constexpr float SOFTCAP = 30.0f;
constexpr int TOK = Bsz * Ssz;  // 4096

DEVI unsigned short f2b(float f) {
  unsigned u = __float_as_uint(f);
  u += 0x7fffu + ((u >> 16) & 1u);
  return (unsigned short)(u >> 16);
}

DEVI void async16(const void* g, void* l) {
  __builtin_amdgcn_global_load_lds(
      (const __attribute__((address_space(1))) unsigned int*)g,
      (__attribute__((address_space(3))) unsigned int*)l, 16, 0, 0);
}

// ---------------- fp32 -> bf16 conversion (all tensors, one kernel) --------
__global__ __launch_bounds__(256) void cvt_all(
    const float* __restrict__ x, const float* __restrict__ wq,
    const float* __restrict__ wk, const float* __restrict__ wv,
    const float* __restrict__ wo, unsigned short* __restrict__ xb,
    unsigned short* __restrict__ wqkv, unsigned short* __restrict__ wob) {
  constexpr int NX = TOK * HID / 4, NQ = NH * Dh * HID / 4,
                NK = NKV * Dh * HID / 4;
  int i = blockIdx.x * 256 + threadIdx.x;
  const float* src;
  unsigned short* dst;
  if (i < NX) { src = x; dst = xb; }
  else if ((i -= NX) < NQ) { src = wq; dst = wqkv; }
  else if ((i -= NQ) < NK) { src = wk; dst = wqkv + NH * Dh * HID; }
  else if ((i -= NK) < NK) { src = wv; dst = wqkv + (NH * Dh + NKV * Dh) * HID; }
  else if ((i -= NK) < NQ) { src = wo; dst = wob; }
  else return;
  float4 v = reinterpret_cast<const float4*>(src)[i];
  ushort4 o2;
  o2.x = f2b(v.x); o2.y = f2b(v.y); o2.z = f2b(v.z); o2.w = f2b(v.w);
  reinterpret_cast<ushort4*>(dst)[i] = o2;
}

// ---------------- bf16 GEMM: C[M][N] = A[M][K] * Bt[N][K]^T, K=1024 --------
// 128x128 tile, BK=32, 4 waves (2x2), m97-style global_load_lds staging.
template <bool F32OUT>
__global__ __launch_bounds__(256) void gemm_bt(
    const unsigned short* __restrict__ A, const unsigned short* __restrict__ Bt,
    void* __restrict__ Cv, int N) {
  constexpr int K = 1024, BK = 32;
  __shared__ unsigned short As[128 * BK];
  __shared__ unsigned short Bs[128 * BK];
  const int t = threadIdx.x;
  const int lane = t & 63, w = t >> 6;
  const int wr = w >> 1, wc = w & 1;
  const int lq = lane & 15, lg = lane >> 4;
  const long arow0 = (long)blockIdx.x * 128;
  const long bcol0 = (long)blockIdx.y * 128;
  const unsigned short* ag = A + (arow0 + (t >> 2)) * K + (t & 3) * 8;
  const unsigned short* bg = Bt + (bcol0 + (t >> 2)) * K + (t & 3) * 8;
  f32x4 acc[4][4] = {};
  for (int kk = 0; kk < K; kk += BK) {
    __syncthreads();
    async16(ag + kk, &As[t * 8]);
    async16(ag + kk + 64 * K, &As[2048 + t * 8]);
    async16(bg + kk, &Bs[t * 8]);
    async16(bg + kk + 64 * K, &Bs[2048 + t * 8]);
    __syncthreads();
    bf16x8 af[4], bfr[4];
#pragma unroll
    for (int m = 0; m < 4; ++m)
      af[m] = *(const bf16x8*)&As[(wr * 64 + m * 16 + lq) * BK + lg * 8];
#pragma unroll
    for (int n = 0; n < 4; ++n)
      bfr[n] = *(const bf16x8*)&Bs[(wc * 64 + n * 16 + lq) * BK + lg * 8];
#pragma unroll
    for (int m = 0; m < 4; ++m)
#pragma unroll
      for (int n = 0; n < 4; ++n)
        acc[m][n] = __builtin_amdgcn_mfma_f32_16x16x32_bf16(af[m], bfr[n],
                                                            acc[m][n], 0, 0, 0);
  }
#pragma unroll
  for (int m = 0; m < 4; ++m)
#pragma unroll
    for (int n = 0; n < 4; ++n)
#pragma unroll
      for (int r = 0; r < 4; ++r) {
        long row = arow0 + wr * 64 + m * 16 + lg * 4 + r;
        long col = bcol0 + wc * 64 + n * 16 + lq;
        if (F32OUT)
          ((float*)Cv)[row * N + col] = acc[m][n][r];
        else
          ((unsigned short*)Cv)[row * N + col] = f2b(acc[m][n][r]);
      }
}

// ---------------- flash attention: softcap + sliding-window causal GQA -----
// grid (S/64, NH, B), 256 thr. Wave w owns 16 queries (q = q0+w*16+lane&15).
// Swapped QK^T: mfma(K,Q) -> S^T, softmax per-lane (q = lane&15).
__global__ __launch_bounds__(256) void attn(
    const unsigned short* __restrict__ qkv, unsigned short* __restrict__ o) {
  constexpr int KB = 64;
  __shared__ unsigned short Ks[KB * Dh];   // [key][dblk ^ (key&7)] swizzled
  __shared__ unsigned short Vsw[KB * Dh];  // [key][dblk ^ (key&7)] (16B blocks)
  __shared__ unsigned short Vt[Dh * KB];   // [d][kblk8 ^ (d&7)] swizzled
  __shared__ unsigned short Pl[4 * 16 * 64];  // per-wave [q][kblk8 ^ (q&7)]
  const int t = threadIdx.x, lane = t & 63, w = t >> 6;
  const int lq = lane & 15, lg = lane >> 4;
  const int qt = blockIdx.x, h = blockIdx.y, b = blockIdx.z;
  const int kh = h >> 2;
  const long tokb = (long)b * Ssz;
  const int q0 = qt * 64;
  const int qi = q0 + w * 16 + lq;
  bf16x8 qf[2];
  {
    const unsigned short* qp = qkv + (tokb + qi) * QKVC + h * Dh + lg * 8;
    qf[0] = *(const bf16x8*)qp;
    qf[1] = *(const bf16x8*)(qp + 32);
  }
  float m_run = -1e30f, l_run = 0.f;
  f32x4 oacc[4] = {};
  unsigned short* pw = &Pl[w * 1024];
  int kstart = q0 - WINDOW + 1;
  if (kstart < 0) kstart = 0;
  kstart &= ~(KB - 1);
  for (int k0 = kstart; k0 <= q0; k0 += KB) {
    __syncthreads();
    {
      // K staged with source-side XOR swizzle (rule 21): LDS dest stays
      // linear (global_load_lds requirement); Ks[row][b] holds logical
      // d-block b ^ (row&7). row+32 keeps row&7, so same xor both halves.
      const unsigned short* kg =
          qkv + (tokb + k0 + (t >> 3)) * QKVC + NH * Dh + kh * Dh +
          (((t & 7) ^ ((t >> 3) & 7)) * 8);
      async16(kg, &Ks[t * 8]);
      async16(kg + 32 * QKVC, &Ks[2048 + t * 8]);
      int vkey = t >> 3, vphys = t & 7;
      const unsigned short* vbase =
          qkv + (tokb + k0) * QKVC + (NH * Dh + NKV * Dh) + kh * Dh;
      async16(vbase + (long)vkey * QKVC + ((vphys ^ (vkey & 7)) * 8),
              &Vsw[t * 8]);
      async16(vbase + (long)(vkey + 32) * QKVC + ((vphys ^ (vkey & 7)) * 8),
              &Vsw[2048 + t * 8]);
    }
    __syncthreads();
    // transpose V: Vsw[key][d] -> Vt[d][key], both sides swizzle-conflict-free
#pragma unroll
    for (int pp = 0; pp < 2; ++pp) {
      int dblk = w + pp * 4;
      bf16x8 vv = *(const bf16x8*)&Vsw[lane * 64 + ((dblk ^ (lane & 7)) * 8)];
#pragma unroll
      for (int e = 0; e < 8; ++e) {
        int d = dblk * 8 + e;
        Vt[d * 64 + (((lane >> 3) ^ e) * 8) + (lane & 7)] = (unsigned short)vv[e];
      }
    }
    __syncthreads();
    // QK^T (swapped): st[kb] holds S^T[key= kb*16+lg*4+r][q= lq]
    f32x4 st[4] = {};
#pragma unroll
    for (int kb = 0; kb < 4; ++kb) {
      bf16x8 kf0 =
          *(const bf16x8*)&Ks[(kb * 16 + lq) * Dh + ((lg ^ (lq & 7)) * 8)];
      bf16x8 kf1 = *(const bf16x8*)&Ks[(kb * 16 + lq) * Dh +
                                       (((lg + 4) ^ (lq & 7)) * 8)];
      st[kb] = __builtin_amdgcn_mfma_f32_16x16x32_bf16(kf0, qf[0], st[kb], 0, 0, 0);
      st[kb] = __builtin_amdgcn_mfma_f32_16x16x32_bf16(kf1, qf[1], st[kb], 0, 0, 0);
    }
    float sc[16];
    float pmax = -1e30f;
#pragma unroll
    for (int kb = 0; kb < 4; ++kb)
#pragma unroll
      for (int r = 0; r < 4; ++r) {
        float s = st[kb][r] * SCALE_;
        float e2 = __expf(s * (2.0f / SOFTCAP));
        s = SOFTCAP * (1.0f - 2.0f / (e2 + 1.0f));  // softcap via tanh
        int j = k0 + kb * 16 + lg * 4 + r;
        bool ok = (j <= qi) & (j > qi - WINDOW);
        s = ok ? s : -1e30f;
        sc[kb * 4 + r] = s;
        pmax = fmaxf(pmax, s);
      }
    pmax = fmaxf(pmax, __shfl_xor(pmax, 16));
    pmax = fmaxf(pmax, __shfl_xor(pmax, 32));
    float m_new = fmaxf(m_run, pmax);
    float alpha = __expf(m_run - m_new);
    float psum = 0.f;
    unsigned short pb[16];
#pragma unroll
    for (int ii = 0; ii < 16; ++ii) {
      float p = (sc[ii] > -1e29f) ? __expf(sc[ii] - m_new) : 0.f;
      psum += p;
      pb[ii] = f2b(p);
    }
    psum += __shfl_xor(psum, 16);
    psum += __shfl_xor(psum, 32);
    l_run = l_run * alpha + psum;
    m_run = m_new;
    // write P (bf16) to per-wave LDS, XOR-block-swizzled
#pragma unroll
    for (int kb = 0; kb < 4; ++kb) {
      bf16x4 pk = {(short)pb[kb * 4], (short)pb[kb * 4 + 1],
                   (short)pb[kb * 4 + 2], (short)pb[kb * 4 + 3]};
      int phys = (kb * 2 + (lg >> 1)) ^ (lq & 7);
      *(bf16x4*)&pw[lq * 64 + phys * 8 + (lg & 1) * 4] = pk;
    }
    // rescale O by alpha (broadcast q-layout alpha via bpermute)
#pragma unroll
    for (int r = 0; r < 4; ++r) {
      float ar = __uint_as_float((unsigned)__builtin_amdgcn_ds_bpermute(
          (lg * 4 + r) * 4, (int)__float_as_uint(alpha)));
#pragma unroll
      for (int db = 0; db < 4; ++db) oacc[db][r] *= ar;
    }
    // PV: O[q][d] += P[q][k] * V[k][d]
#pragma unroll
    for (int s2 = 0; s2 < 2; ++s2) {
      bf16x8 pa = *(const bf16x8*)&pw[lq * 64 + (((s2 * 4 + lg) ^ (lq & 7)) * 8)];
#pragma unroll
      for (int db = 0; db < 4; ++db) {
        const int d = db * 16 + lq;
        bf16x8 vb = *(const bf16x8*)&Vt[d * 64 + (((s2 * 4 + lg) ^ (lq & 7)) * 8)];
        oacc[db] = __builtin_amdgcn_mfma_f32_16x16x32_bf16(pa, vb, oacc[db], 0, 0, 0);
      }
    }
  }
  // epilogue: divide by l, store bf16
#pragma unroll
  for (int r = 0; r < 4; ++r) {
    float lr = __uint_as_float((unsigned)__builtin_amdgcn_ds_bpermute(
        (lg * 4 + r) * 4, (int)__float_as_uint(l_run)));
    float inv = 1.0f / lr;
    long row = tokb + q0 + w * 16 + lg * 4 + r;
#pragma unroll
    for (int db = 0; db < 4; ++db)
      o[row * (NH * Dh) + h * Dh + db * 16 + lq] = f2b(oacc[db][r] * inv);
  }
}

extern "C" void kernel_launch(void* const* d_in, const int* in_sizes, int n_in,
                              void* d_out, int out_size, void* d_ws,
                              size_t ws_size, hipStream_t stream) {
  const float* x = (const float*)d_in[0];
  const float* wq = (const float*)d_in[1];
  const float* wk = (const float*)d_in[2];
  const float* wv = (const float*)d_in[3];
  const float* wo = (const float*)d_in[4];
  char* ws = (char*)d_ws;
  // Compact ws layout (peak 13 MB — round-4 post-timing divergence pointed
  // at ws overflow corrupting the harness's pristine input copies):
  //   ws[ 0..8MB)  xb (bf16 x), later reused as ob (attn output)
  //   ws[ 8..11MB) wqkv (bf16 Wq|Wk|Wv)
  //   ws[11..13MB) wob  (bf16 Wo)
  // qkvb (12 MB bf16) lives in d_out (16 MB f32): written by QKV GEMM,
  // consumed by attn, then d_out is fully overwritten by the final f32 GEMM
  // (which never reads d_out — no in-place hazard; stream-ordered).
  unsigned short* xb = (unsigned short*)(ws);                        // TOK*HID
  unsigned short* ob = (unsigned short*)(ws);                        // TOK*HID
  unsigned short* wqkv = (unsigned short*)(ws + 8l * 1024 * 1024);   // 1536*1024
  unsigned short* wob = (unsigned short*)(ws + 11l * 1024 * 1024);   // 1024*1024
  unsigned short* qkvb = (unsigned short*)d_out;                     // TOK*1536
  float* out = (float*)d_out;  // reference output dtype is float32

  cvt_all<<<6656, 256, 0, stream>>>(x, wq, wk, wv, wo, xb, wqkv, wob);
  gemm_bt<false><<<dim3(TOK / 128, QKVC / 128), 256, 0, stream>>>(xb, wqkv, qkvb, QKVC);
  attn<<<dim3(Ssz / 64, NH, Bsz), 256, 0, stream>>>(qkvb, ob);
  gemm_bt<true><<<dim3(TOK / 128, HID / 128), 256, 0, stream>>>(ob, wob, out, HID);
}

// Round 9
// 210.938 us; speedup vs baseline: 1.0457x; 1.0457x over previous
//
#include <hip/hip_runtime.h>

typedef __attribute__((ext_vector_type(8))) short bf16x8;
typedef __attribute__((ext_vector_type(4))) short bf16x4;
typedef __attribute__((ext_vector_type(4))) float f32x4;

#define DEVI __device__ __forceinline__

constexpr int Bsz = 2, Ssz = 2048, HID = 1024, NH = 16, NKV = 4, Dh = 64;
constexpr int QKVC = NH * Dh + 2 * NKV * Dh;  // 1536
constexpr int WINDOW = 1024;
constexpr float SCALE_ = 0.125f;
constexpr float SOFTCAP = 30.0f;
constexpr int TOK = Bsz * Ssz;  // 4096

DEVI unsigned short f2b(float f) {
  unsigned u = __float_as_uint(f);
  u += 0x7fffu + ((u >> 16) & 1u);
  return (unsigned short)(u >> 16);
}

DEVI void async16(const void* g, void* l) {
  __builtin_amdgcn_global_load_lds(
      (const __attribute__((address_space(1))) unsigned int*)g,
      (__attribute__((address_space(3))) unsigned int*)l, 16, 0, 0);
}

// ---------------- fp32 -> bf16 conversion (all tensors, one kernel) --------
__global__ __launch_bounds__(256) void cvt_all(
    const float* __restrict__ x, const float* __restrict__ wq,
    const float* __restrict__ wk, const float* __restrict__ wv,
    const float* __restrict__ wo, unsigned short* __restrict__ xb,
    unsigned short* __restrict__ wqkv, unsigned short* __restrict__ wob) {
  constexpr int NX = TOK * HID / 4, NQ = NH * Dh * HID / 4,
                NK = NKV * Dh * HID / 4;
  int i = blockIdx.x * 256 + threadIdx.x;
  const float* src;
  unsigned short* dst;
  if (i < NX) { src = x; dst = xb; }
  else if ((i -= NX) < NQ) { src = wq; dst = wqkv; }
  else if ((i -= NQ) < NK) { src = wk; dst = wqkv + NH * Dh * HID; }
  else if ((i -= NK) < NK) { src = wv; dst = wqkv + (NH * Dh + NKV * Dh) * HID; }
  else if ((i -= NK) < NQ) { src = wo; dst = wob; }
  else return;
  float4 v = reinterpret_cast<const float4*>(src)[i];
  ushort4 o2;
  o2.x = f2b(v.x); o2.y = f2b(v.y); o2.z = f2b(v.z); o2.w = f2b(v.w);
  reinterpret_cast<ushort4*>(dst)[i] = o2;
}

// ---------------- bf16 GEMM: C[M][N] = A[M][K] * Bt[N][K]^T, K=1024 --------
// 128x128 tile, BK=32, 4 waves (2x2), m97-style global_load_lds staging.
template <bool F32OUT>
__global__ __launch_bounds__(256) void gemm_bt(
    const unsigned short* __restrict__ A, const unsigned short* __restrict__ Bt,
    void* __restrict__ Cv, int N) {
  constexpr int K = 1024, BK = 32;
  __shared__ unsigned short As[128 * BK];
  __shared__ unsigned short Bs[128 * BK];
  const int t = threadIdx.x;
  const int lane = t & 63, w = t >> 6;
  const int wr = w >> 1, wc = w & 1;
  const int lq = lane & 15, lg = lane >> 4;
  const long arow0 = (long)blockIdx.x * 128;
  const long bcol0 = (long)blockIdx.y * 128;
  const unsigned short* ag = A + (arow0 + (t >> 2)) * K + (t & 3) * 8;
  const unsigned short* bg = Bt + (bcol0 + (t >> 2)) * K + (t & 3) * 8;
  f32x4 acc[4][4] = {};
  for (int kk = 0; kk < K; kk += BK) {
    __syncthreads();
    async16(ag + kk, &As[t * 8]);
    async16(ag + kk + 64 * K, &As[2048 + t * 8]);
    async16(bg + kk, &Bs[t * 8]);
    async16(bg + kk + 64 * K, &Bs[2048 + t * 8]);
    __syncthreads();
    bf16x8 af[4], bfr[4];
#pragma unroll
    for (int m = 0; m < 4; ++m)
      af[m] = *(const bf16x8*)&As[(wr * 64 + m * 16 + lq) * BK + lg * 8];
#pragma unroll
    for (int n = 0; n < 4; ++n)
      bfr[n] = *(const bf16x8*)&Bs[(wc * 64 + n * 16 + lq) * BK + lg * 8];
#pragma unroll
    for (int m = 0; m < 4; ++m)
#pragma unroll
      for (int n = 0; n < 4; ++n)
        acc[m][n] = __builtin_amdgcn_mfma_f32_16x16x32_bf16(af[m], bfr[n],
                                                            acc[m][n], 0, 0, 0);
  }
#pragma unroll
  for (int m = 0; m < 4; ++m)
#pragma unroll
    for (int n = 0; n < 4; ++n)
#pragma unroll
      for (int r = 0; r < 4; ++r) {
        long row = arow0 + wr * 64 + m * 16 + lg * 4 + r;
        long col = bcol0 + wc * 64 + n * 16 + lq;
        if (F32OUT)
          ((float*)Cv)[row * N + col] = acc[m][n][r];
        else
          ((unsigned short*)Cv)[row * N + col] = f2b(acc[m][n][r]);
      }
}

// ---------------- V transpose: qkvb V region -> vT[b][kh][d][s] ----------
// grid (Ssz/64, NKV, Bsz), 256 thr. 64x64 tile via swizzled LDS.
__global__ __launch_bounds__(256) void vtrans(
    const unsigned short* __restrict__ qkv, unsigned short* __restrict__ vT) {
  __shared__ unsigned short Vsw[64 * 64];  // [s][dblk ^ (s&7)]
  const int t = threadIdx.x;
  const int s0 = blockIdx.x * 64, kh = blockIdx.y, b = blockIdx.z;
  const unsigned short* vg =
      qkv + ((long)b * Ssz + s0 + (t >> 3)) * QKVC + (NH * Dh + NKV * Dh) +
      kh * Dh + (((t & 7) ^ ((t >> 3) & 7)) * 8);
  async16(vg, &Vsw[t * 8]);
  async16(vg + 32 * QKVC, &Vsw[2048 + t * 8]);
  __syncthreads();
  const int d = t >> 2, sc_ = t & 3;
  bf16x8 o0, o1;
#pragma unroll
  for (int j = 0; j < 8; ++j) {
    int s = sc_ * 16 + j;
    o0[j] = (short)Vsw[s * 64 + (((d >> 3) ^ (s & 7)) * 8) + (d & 7)];
    int s2 = s + 8;
    o1[j] = (short)Vsw[s2 * 64 + (((d >> 3) ^ (s2 & 7)) * 8) + (d & 7)];
  }
  long orow = ((long)(b * NKV + kh) * Dh + d) * Ssz + s0 + sc_ * 16;
  *(bf16x8*)&vT[orow] = o0;
  *(bf16x8*)&vT[orow + 8] = o1;
}

// ---------------- flash attention: softcap + sliding-window causal GQA -----
// grid (S/64, NH, B), 256 thr. Wave w owns 16 queries (q = q0+w*16+lane&15).
// Swapped QK^T: mfma(K,Q) -> S^T, softmax per-lane (q = lane&15).
// 2-phase pipeline: double-buffered K/V^T staging overlaps compute.
__global__ __launch_bounds__(256) void attn(
    const unsigned short* __restrict__ qkv,
    const unsigned short* __restrict__ vT, unsigned short* __restrict__ o) {
  constexpr int KB = 64;
  __shared__ unsigned short Ks[2][KB * Dh];  // [key][dblk ^ (key&7)]
  __shared__ unsigned short Vt[2][Dh * KB];  // [d][kblk ^ (d&7)]
  __shared__ unsigned short Pl[4 * 16 * 64]; // per-wave [q][kblk8 ^ (q&7)]
  const int t = threadIdx.x, lane = t & 63, w = t >> 6;
  const int lq = lane & 15, lg = lane >> 4;
  const int qt = blockIdx.x, h = blockIdx.y, b = blockIdx.z;
  const int kh = h >> 2;
  const long tokb = (long)b * Ssz;
  const int q0 = qt * 64;
  const int qi = q0 + w * 16 + lq;
  const int qlo = q0 + w * 16;
  bf16x8 qf[2];
  {
    const unsigned short* qp = qkv + (tokb + qi) * QKVC + h * Dh + lg * 8;
    qf[0] = *(const bf16x8*)qp;
    qf[1] = *(const bf16x8*)(qp + 32);
  }
  // staging source pointers (pre-swizzled; advance by k0)
  const unsigned short* kg0 = qkv + (tokb + (t >> 3)) * QKVC + NH * Dh +
                              kh * Dh + (((t & 7) ^ ((t >> 3) & 7)) * 8);
  const unsigned short* vg0 = vT + ((long)(b * NKV + kh) * Dh + (t >> 3)) * Ssz +
                              (((t & 7) ^ ((t >> 3) & 7)) * 8);
  float m_run = -1e30f, l_run = 0.f;
  f32x4 oacc[4] = {};
  unsigned short* pw = &Pl[w * 1024];
  int kstart = q0 - WINDOW + 1;
  if (kstart < 0) kstart = 0;
  kstart &= ~(KB - 1);

#define STAGE(buf, kk)                                    \
  do {                                                    \
    async16(kg0 + (long)(kk)*QKVC, &Ks[buf][t * 8]);      \
    async16(kg0 + (long)((kk) + 32) * QKVC,               \
            &Ks[buf][2048 + t * 8]);                      \
    async16(vg0 + (kk), &Vt[buf][t * 8]);                 \
    async16(vg0 + (kk) + 32 * Ssz, &Vt[buf][2048 + t * 8]); \
  } while (0)

  STAGE(0, kstart);
  __syncthreads();
  int cur = 0;
  for (int k0 = kstart; k0 <= q0; k0 += KB) {
    if (k0 + KB <= q0) STAGE(cur ^ 1, k0 + KB);
    // QK^T (swapped): st[kb] holds S^T[key= kb*16+lg*4+r][q= lq]
    f32x4 st[4] = {};
#pragma unroll
    for (int kb = 0; kb < 4; ++kb) {
      bf16x8 kf0 = *(const bf16x8*)&Ks[cur][(kb * 16 + lq) * Dh +
                                           ((lg ^ (lq & 7)) * 8)];
      bf16x8 kf1 = *(const bf16x8*)&Ks[cur][(kb * 16 + lq) * Dh +
                                            (((lg + 4) ^ (lq & 7)) * 8)];
      st[kb] = __builtin_amdgcn_mfma_f32_16x16x32_bf16(kf0, qf[0], st[kb], 0, 0, 0);
      st[kb] = __builtin_amdgcn_mfma_f32_16x16x32_bf16(kf1, qf[1], st[kb], 0, 0, 0);
    }
    const bool need_mask = (k0 + KB - 1 > qlo) | (k0 <= qlo + 15 - WINDOW);
    float sc[16];
    float pmax = -1e30f;
    if (need_mask) {
#pragma unroll
      for (int kb = 0; kb < 4; ++kb)
#pragma unroll
        for (int r = 0; r < 4; ++r) {
          float s = st[kb][r] * SCALE_;
          float e2 = __expf(s * (2.0f / SOFTCAP));
          s = SOFTCAP * (1.0f - 2.0f / (e2 + 1.0f));
          int j = k0 + kb * 16 + lg * 4 + r;
          bool ok = (j <= qi) & (j > qi - WINDOW);
          s = ok ? s : -1e30f;
          sc[kb * 4 + r] = s;
          pmax = fmaxf(pmax, s);
        }
    } else {
#pragma unroll
      for (int kb = 0; kb < 4; ++kb)
#pragma unroll
        for (int r = 0; r < 4; ++r) {
          float s = st[kb][r] * SCALE_;
          float e2 = __expf(s * (2.0f / SOFTCAP));
          s = SOFTCAP * (1.0f - 2.0f / (e2 + 1.0f));
          sc[kb * 4 + r] = s;
          pmax = fmaxf(pmax, s);
        }
    }
    pmax = fmaxf(pmax, __shfl_xor(pmax, 16));
    pmax = fmaxf(pmax, __shfl_xor(pmax, 32));
    float m_new = fmaxf(m_run, pmax);
    float alpha = __expf(m_run - m_new);
    float psum = 0.f;
    unsigned short pb[16];
    if (need_mask) {
#pragma unroll
      for (int ii = 0; ii < 16; ++ii) {
        float p = (sc[ii] > -1e29f) ? __expf(sc[ii] - m_new) : 0.f;
        psum += p;
        pb[ii] = f2b(p);
      }
    } else {
#pragma unroll
      for (int ii = 0; ii < 16; ++ii) {
        float p = __expf(sc[ii] - m_new);
        psum += p;
        pb[ii] = f2b(p);
      }
    }
    psum += __shfl_xor(psum, 16);
    psum += __shfl_xor(psum, 32);
    l_run = l_run * alpha + psum;
    m_run = m_new;
    // write P (bf16) to per-wave LDS, XOR-block-swizzled
#pragma unroll
    for (int kb = 0; kb < 4; ++kb) {
      bf16x4 pk = {(short)pb[kb * 4], (short)pb[kb * 4 + 1],
                   (short)pb[kb * 4 + 2], (short)pb[kb * 4 + 3]};
      int phys = (kb * 2 + (lg >> 1)) ^ (lq & 7);
      *(bf16x4*)&pw[lq * 64 + phys * 8 + (lg & 1) * 4] = pk;
    }
    // rescale O by alpha (broadcast q-layout alpha via bpermute)
#pragma unroll
    for (int r = 0; r < 4; ++r) {
      float ar = __uint_as_float((unsigned)__builtin_amdgcn_ds_bpermute(
          (lg * 4 + r) * 4, (int)__float_as_uint(alpha)));
#pragma unroll
      for (int db = 0; db < 4; ++db) oacc[db][r] *= ar;
    }
    // PV: O[q][d] += P[q][k] * V[k][d]
#pragma unroll
    for (int s2 = 0; s2 < 2; ++s2) {
      bf16x8 pa = *(const bf16x8*)&pw[lq * 64 + (((s2 * 4 + lg) ^ (lq & 7)) * 8)];
#pragma unroll
      for (int db = 0; db < 4; ++db) {
        const int d = db * 16 + lq;
        bf16x8 vb = *(const bf16x8*)&Vt[cur][d * 64 +
                                            (((s2 * 4 + lg) ^ (lq & 7)) * 8)];
        oacc[db] = __builtin_amdgcn_mfma_f32_16x16x32_bf16(pa, vb, oacc[db], 0, 0, 0);
      }
    }
    __syncthreads();  // drains prefetch vmcnt; guards buffer reuse
    cur ^= 1;
  }
#undef STAGE
  // epilogue: divide by l, store bf16
#pragma unroll
  for (int r = 0; r < 4; ++r) {
    float lr = __uint_as_float((unsigned)__builtin_amdgcn_ds_bpermute(
        (lg * 4 + r) * 4, (int)__float_as_uint(l_run)));
    float inv = 1.0f / lr;
    long row = tokb + q0 + w * 16 + lg * 4 + r;
#pragma unroll
    for (int db = 0; db < 4; ++db)
      o[row * (NH * Dh) + h * Dh + db * 16 + lq] = f2b(oacc[db][r] * inv);
  }
}

extern "C" void kernel_launch(void* const* d_in, const int* in_sizes, int n_in,
                              void* d_out, int out_size, void* d_ws,
                              size_t ws_size, hipStream_t stream) {
  const float* x = (const float*)d_in[0];
  const float* wq = (const float*)d_in[1];
  const float* wk = (const float*)d_in[2];
  const float* wv = (const float*)d_in[3];
  const float* wo = (const float*)d_in[4];
  char* ws = (char*)d_ws;
  // ws layout (peak 13 MB):
  //   ws[ 0..8MB)  xb (bf16 x), later reused as ob (attn output)
  //   ws[ 8..11MB) wqkv (bf16 Wq|Wk|Wv)
  //   ws[11..13MB) wob  (bf16 Wo)
  // d_out (16 MB f32) carries: qkvb [0..12MB) + vT [12..14MB), both dead
  // before the final f32 GEMM overwrites d_out (which never reads d_out).
  unsigned short* xb = (unsigned short*)(ws);                        // TOK*HID
  unsigned short* ob = (unsigned short*)(ws);                        // TOK*HID
  unsigned short* wqkv = (unsigned short*)(ws + 8l * 1024 * 1024);   // 1536*1024
  unsigned short* wob = (unsigned short*)(ws + 11l * 1024 * 1024);   // 1024*1024
  unsigned short* qkvb = (unsigned short*)d_out;                     // TOK*1536
  unsigned short* vT =
      (unsigned short*)((char*)d_out + 12l * 1024 * 1024);  // B*NKV*Dh*Ssz
  float* out = (float*)d_out;  // reference output dtype is float32

  cvt_all<<<6656, 256, 0, stream>>>(x, wq, wk, wv, wo, xb, wqkv, wob);
  gemm_bt<false><<<dim3(TOK / 128, QKVC / 128), 256, 0, stream>>>(xb, wqkv, qkvb, QKVC);
  vtrans<<<dim3(Ssz / 64, NKV, Bsz), 256, 0, stream>>>(qkvb, vT);
  attn<<<dim3(Ssz / 64, NH, Bsz), 256, 0, stream>>>(qkvb, vT, ob);
  gemm_bt<true><<<dim3(TOK / 128, HID / 128), 256, 0, stream>>>(ob, wob, out, HID);
}